// Round 9
// baseline (942.545 us; speedup 1.0000x reference)
//
#include <hip/hip_runtime.h>
#include <math.h>

#define N_NODES 100000
#define N_EDGES 800000
#define NPAD    100096   // 782 * 128
#define FDIM 256
#define HEADS 8
#define CDIM 32
#define OUTF 128

#define SCAN_BLOCK 256
#define SCAN_NBLK ((N_NODES + SCAN_BLOCK - 1) / SCAN_BLOCK)   // 391

typedef short  s16x8 __attribute__((ext_vector_type(8)));
typedef float  f32x4 __attribute__((ext_vector_type(4)));
typedef unsigned short u16;

__device__ __forceinline__ u16 f2bf(float f) {
    unsigned u = __float_as_uint(f);
    unsigned r = (u + 0x7fff + ((u >> 16) & 1)) >> 16;
    return (u16)r;
}
__device__ __forceinline__ float bf2f(u16 h) {
    return __uint_as_float(((unsigned)h) << 16);
}

__device__ __forceinline__ void gload_lds16(const void* g, void* l) {
    __builtin_amdgcn_global_load_lds((const __attribute__((address_space(1))) void*)g,
                                     (__attribute__((address_space(3))) void*)l, 16, 0, 0);
}

// ---------------- split f32 -> bf16 hi/lo (pad region zeroed) ----------------
__global__ void split_hilo(const float* __restrict__ src, int n_valid4, int n_pad4,
                           u16* __restrict__ hi, u16* __restrict__ lo) {
    int i = blockIdx.x * blockDim.x + threadIdx.x;
    int stride = gridDim.x * blockDim.x;
    for (; i < n_pad4; i += stride) {
        f32x4 v = {0.f, 0.f, 0.f, 0.f};
        if (i < n_valid4) v = ((const f32x4*)src)[i];
        u16 h[4], l[4];
#pragma unroll
        for (int j = 0; j < 4; j++) {
            float f = v[j];
            h[j] = f2bf(f);
            l[j] = f2bf(f - bf2f(h[j]));
        }
        ((ushort4*)hi)[i] = make_ushort4(h[0], h[1], h[2], h[3]);
        ((ushort4*)lo)[i] = make_ushort4(l[0], l[1], l[2], l[3]);
    }
}

// ---------------- W prep: transpose + concat + split ----------------
__global__ void prep_w_layer(const float* __restrict__ Wl, const float* __restrict__ Wr,
                             u16* __restrict__ WtH, u16* __restrict__ WtL) {
    int idx = blockIdx.x * blockDim.x + threadIdx.x;
    if (idx >= 512 * 256) return;
    int n = idx >> 8, k = idx & 255;
    float w = (n < 256) ? Wl[k * 256 + n] : Wr[k * 256 + (n - 256)];
    u16 h = f2bf(w);
    WtH[idx] = h;
    WtL[idx] = f2bf(w - bf2f(h));
}

__global__ void prep_w_fc(const float* __restrict__ Wfc,
                          u16* __restrict__ WtH, u16* __restrict__ WtL) {
    int idx = blockIdx.x * blockDim.x + threadIdx.x;
    if (idx >= 128 * 256) return;
    int n = idx >> 8, k = idx & 255;
    float w = Wfc[k * 128 + n];
    u16 h = f2bf(w);
    WtH[idx] = h;
    WtL[idx] = f2bf(w - bf2f(h));
}

// ---------------- 3-term split-precision bf16 MFMA GEMM ----------------
__global__ __launch_bounds__(256) void gemm3(
        const u16* __restrict__ Ah, const u16* __restrict__ Al,
        const u16* __restrict__ WtH, const u16* __restrict__ WtL,
        const float* __restrict__ bias0, const float* __restrict__ bias1,
        float* __restrict__ C0, float* __restrict__ C1, int ldc, int M) {
    __shared__ __align__(16) u16 lA[128 * 64];
    __shared__ __align__(16) u16 lB[128 * 64];

    int tid = threadIdx.x;
    int wid = tid >> 6, lane = tid & 63;
    int wm = wid >> 1, wn = wid & 1;
    int m0 = blockIdx.x * 128, n0 = blockIdx.y * 128;
    int lr = lane & 15, lk = lane >> 4;

    f32x4 acc[4][4] = {};

#pragma unroll 1
    for (int seg = 0; seg < 3; seg++) {
        const u16* As = (seg == 1) ? Al : Ah;
        const u16* Ws = (seg == 2) ? WtL : WtH;
#pragma unroll 1
        for (int k0 = 0; k0 < 256; k0 += 64) {
#pragma unroll
            for (int i = 0; i < 4; i++) {
                int t = i * 256 + tid;
                int row = t >> 3;
                int ch = (t & 7) ^ (row & 7);
                gload_lds16(As + (size_t)(m0 + row) * 256 + k0 + ch * 8,
                            (char*)lA + i * 4096 + wid * 1024);
            }
#pragma unroll
            for (int i = 0; i < 4; i++) {
                int t = i * 256 + tid;
                int row = t >> 3;
                int ch = (t & 7) ^ (row & 7);
                gload_lds16(Ws + (size_t)(n0 + row) * 256 + k0 + ch * 8,
                            (char*)lB + i * 4096 + wid * 1024);
            }
            __syncthreads();

#pragma unroll
            for (int kk = 0; kk < 2; kk++) {
                s16x8 af[4], bf[4];
#pragma unroll
                for (int mr = 0; mr < 4; mr++) {
                    int r = wm * 64 + mr * 16 + lr;
                    int q = (kk * 4 + lk) ^ (r & 7);
                    af[mr] = *(const s16x8*)&lA[r * 64 + q * 8];
                }
#pragma unroll
                for (int nr = 0; nr < 4; nr++) {
                    int r = wn * 64 + nr * 16 + lr;
                    int q = (kk * 4 + lk) ^ (r & 7);
                    bf[nr] = *(const s16x8*)&lB[r * 64 + q * 8];
                }
#pragma unroll
                for (int mr = 0; mr < 4; mr++)
#pragma unroll
                    for (int nr = 0; nr < 4; nr++)
                        acc[mr][nr] = __builtin_amdgcn_mfma_f32_16x16x32_bf16(
                            af[mr], bf[nr], acc[mr][nr], 0, 0, 0);
            }
            __syncthreads();
        }
    }

#pragma unroll
    for (int mr = 0; mr < 4; mr++) {
#pragma unroll
        for (int nr = 0; nr < 4; nr++) {
            int col = n0 + wn * 64 + nr * 16 + lr;
            float* Cp; const float* bp; int c;
            if (col < 256) { Cp = C0; bp = bias0; c = col; }
            else           { Cp = C1; bp = bias1; c = col - 256; }
            float b = bp[c];
#pragma unroll
            for (int j = 0; j < 4; j++) {
                int row = m0 + wm * 64 + mr * 16 + lk * 4 + j;
                if (row < M) Cp[(size_t)row * ldc + c] = acc[mr][nr][j] + b;
            }
        }
    }
}

// ---------------- CSR build ----------------
__global__ void count_deg(const int* __restrict__ dstA, int* __restrict__ deg) {
    int i = blockIdx.x * blockDim.x + threadIdx.x;
    int stride = gridDim.x * blockDim.x;
    for (; i < N_EDGES; i += stride) atomicAdd(&deg[dstA[i]], 1);
}

__global__ void scan_phase1(const int* __restrict__ deg, int* __restrict__ blocksum) {
    __shared__ int sdata[SCAN_BLOCK];
    int i = blockIdx.x * SCAN_BLOCK + threadIdx.x;
    sdata[threadIdx.x] = (i < N_NODES) ? deg[i] : 0;
    __syncthreads();
    for (int off = SCAN_BLOCK / 2; off > 0; off >>= 1) {
        if (threadIdx.x < off) sdata[threadIdx.x] += sdata[threadIdx.x + off];
        __syncthreads();
    }
    if (threadIdx.x == 0) blocksum[blockIdx.x] = sdata[0];
}

__global__ void scan_phase2(int* __restrict__ blocksum) {
    __shared__ int part[512];
    int t = threadIdx.x;
    int v = (t < SCAN_NBLK) ? blocksum[t] : 0;
    part[t] = v;
    __syncthreads();
    for (int off = 1; off < 512; off <<= 1) {
        int u = 0;
        if (t >= off) u = part[t - off];
        __syncthreads();
        if (t >= off) part[t] += u;
        __syncthreads();
    }
    if (t < SCAN_NBLK) blocksum[t] = part[t] - v;   // exclusive
}

__global__ void scan_phase3(const int* __restrict__ deg, const int* __restrict__ blockoff,
                            int* __restrict__ rowstart, int* __restrict__ cursor) {
    __shared__ int part[SCAN_BLOCK];
    int t = threadIdx.x;
    int i = blockIdx.x * SCAN_BLOCK + t;
    int v = (i < N_NODES) ? deg[i] : 0;
    part[t] = v;
    __syncthreads();
    for (int off = 1; off < SCAN_BLOCK; off <<= 1) {
        int u = 0;
        if (t >= off) u = part[t - off];
        __syncthreads();
        if (t >= off) part[t] += u;
        __syncthreads();
    }
    if (i < N_NODES) {
        int excl = blockoff[blockIdx.x] + part[t] - v;
        rowstart[i] = excl;
        cursor[i] = excl;
        if (i == N_NODES - 1) rowstart[N_NODES] = blockoff[blockIdx.x] + part[t];
    }
}

__global__ void fill_csr(const int* __restrict__ srcA, const int* __restrict__ dstA,
                         int* __restrict__ cursor, int* __restrict__ csr_src) {
    int i = blockIdx.x * blockDim.x + threadIdx.x;
    int stride = gridDim.x * blockDim.x;
    for (; i < N_EDGES; i += stride) {
        int pos = atomicAdd(&cursor[dstA[i]], 1);
        csr_src[pos] = srcA[i];
    }
}

// ---------------- Fused GATv2 edge phase (one wave per destination) ----------------
// float4-per-lane layout; depth-3 pipeline on the row gathers; nt hints keep the
// reused xl table L3-resident by streaming xr/out past the caches.
__global__ void gat_fused(const float* __restrict__ xl, const float* __restrict__ xr,
                          const int* __restrict__ rowstart, const int* __restrict__ csr_src,
                          const float* __restrict__ att, float* __restrict__ out) {
    int wid = (blockIdx.x * blockDim.x + threadIdx.x) >> 6;
    int lane = threadIdx.x & 63;
    if (wid >= N_NODES) return;

    f32x4 xrv  = __builtin_nontemporal_load((const f32x4*)(xr + (size_t)wid * FDIM + lane * 4));
    f32x4 attv = *(const f32x4*)(att + lane * 4);
    f32x4 acc = {0.f, 0.f, 0.f, 0.f};
    float den = 0.f;

    int jb = rowstart[wid], je = rowstart[wid + 1];
    if (jb < je) {
        int jlast = je - 1;
        // pipeline depth 3: hold rows j, j+1, j+2; load j+3
        f32x4 xv0 = *(const f32x4*)(xl + (size_t)csr_src[jb] * FDIM + lane * 4);
        int j1 = (jb + 1 <= jlast) ? jb + 1 : jlast;
        f32x4 xv1 = *(const f32x4*)(xl + (size_t)csr_src[j1] * FDIM + lane * 4);
        int j2 = (jb + 2 <= jlast) ? jb + 2 : jlast;
        f32x4 xv2 = *(const f32x4*)(xl + (size_t)csr_src[j2] * FDIM + lane * 4);

        for (int j = jb; j < je; ++j) {
            int j3 = (j + 3 <= jlast) ? j + 3 : jlast;
            f32x4 nxt = *(const f32x4*)(xl + (size_t)csr_src[j3] * FDIM + lane * 4);

            float s = 0.f;
#pragma unroll
            for (int i = 0; i < 4; i++) {
                float v = xv0[i] + xrv[i];
                v = v > 0.f ? v : 0.2f * v;
                s += v * attv[i];
            }
            // reduce over the 8-lane head group (head = lane>>3)
            s += __shfl_xor(s, 1);
            s += __shfl_xor(s, 2);
            s += __shfl_xor(s, 4);
            float e = __expf(s);
            den += e;
#pragma unroll
            for (int i = 0; i < 4; i++) acc[i] += e * xv0[i];
            xv0 = xv1;
            xv1 = xv2;
            xv2 = nxt;
        }
    }
    float inv = 1.f / (den + 1e-16f);
    f32x4 o;
#pragma unroll
    for (int i = 0; i < 4; i++) o[i] = acc[i] * inv;
    __builtin_nontemporal_store(o, (f32x4*)(out + (size_t)wid * FDIM + lane * 4));
}

// ---------------- BatchNorm ----------------
__global__ void bn_stats(const float* __restrict__ X, float* __restrict__ sum,
                         float* __restrict__ sumsq, int nrows) {
    int col = threadIdx.x;
    float s = 0.f, ss = 0.f;
    for (int r = blockIdx.x; r < nrows; r += gridDim.x) {
        float v = X[(size_t)r * FDIM + col];
        s += v;
        ss += v * v;
    }
    atomicAdd(&sum[col], s);
    atomicAdd(&sumsq[col], ss);
}

__global__ void bn_finalize(const float* __restrict__ sum, const float* __restrict__ sumsq,
                            const float* __restrict__ gamma, const float* __restrict__ beta,
                            float* __restrict__ scale, float* __restrict__ shift) {
    int c = threadIdx.x;
    float mean = sum[c] * (1.f / N_NODES);
    float var = sumsq[c] * (1.f / N_NODES) - mean * mean;
    float sc = gamma[c] * rsqrtf(var + 1e-5f);
    scale[c] = sc;
    shift[c] = beta[c] - mean * sc;
}

// BN + ELU fused, output split to bf16 hi/lo (pad rows zeroed)
__global__ void bn_elu_split(const float* __restrict__ X, const float* __restrict__ scale,
                             const float* __restrict__ shift,
                             u16* __restrict__ hi, u16* __restrict__ lo) {
    int i = blockIdx.x * blockDim.x + threadIdx.x;   // float4 units
    int stride = gridDim.x * blockDim.x;
    const int n_valid4 = N_NODES * FDIM / 4;
    const int n_pad4 = NPAD * FDIM / 4;
    for (; i < n_pad4; i += stride) {
        u16 h[4], l[4];
        if (i < n_valid4) {
            f32x4 v = ((const f32x4*)X)[i];
            int c0 = (i * 4) & (FDIM - 1);
#pragma unroll
            for (int j = 0; j < 4; j++) {
                float f = v[j] * scale[c0 + j] + shift[c0 + j];
                f = f > 0.f ? f : expf(f) - 1.f;
                h[j] = f2bf(f);
                l[j] = f2bf(f - bf2f(h[j]));
            }
        } else {
#pragma unroll
            for (int j = 0; j < 4; j++) { h[j] = 0; l[j] = 0; }
        }
        ((ushort4*)hi)[i] = make_ushort4(h[0], h[1], h[2], h[3]);
        ((ushort4*)lo)[i] = make_ushort4(l[0], l[1], l[2], l[3]);
    }
}

// ---------------- Row L2 normalize ----------------
__global__ void l2norm(float* __restrict__ Y, int nrows) {
    int gtid = blockIdx.x * blockDim.x + threadIdx.x;
    int wave = gtid >> 6;
    int lane = threadIdx.x & 63;
    int nwaves = (gridDim.x * blockDim.x) >> 6;
    for (int r = wave; r < nrows; r += nwaves) {
        float v0 = Y[(size_t)r * OUTF + lane];
        float v1 = Y[(size_t)r * OUTF + 64 + lane];
        float ss = v0 * v0 + v1 * v1;
        ss += __shfl_xor(ss, 32);
        ss += __shfl_xor(ss, 16);
        ss += __shfl_xor(ss, 8);
        ss += __shfl_xor(ss, 4);
        ss += __shfl_xor(ss, 2);
        ss += __shfl_xor(ss, 1);
        float inv = 1.f / fmaxf(sqrtf(ss), 1e-12f);
        Y[(size_t)r * OUTF + lane] = v0 * inv;
        Y[(size_t)r * OUTF + 64 + lane] = v1 * inv;
    }
}

extern "C" void kernel_launch(void* const* d_in, const int* in_sizes, int n_in,
                              void* d_out, int out_size, void* d_ws, size_t ws_size,
                              hipStream_t stream) {
    const float* x     = (const float*)d_in[0];
    const int*   ei    = (const int*)d_in[1];
    const float* Wl1   = (const float*)d_in[2];
    const float* bl1   = (const float*)d_in[3];
    const float* Wr1   = (const float*)d_in[4];
    const float* br1   = (const float*)d_in[5];
    const float* att1  = (const float*)d_in[6];
    // d_in[7] = bias1 : cancels exactly inside batchnorm -> skipped
    const float* gamma1 = (const float*)d_in[8];
    const float* beta1  = (const float*)d_in[9];
    const float* Wl2   = (const float*)d_in[10];
    const float* bl2   = (const float*)d_in[11];
    const float* Wr2   = (const float*)d_in[12];
    const float* br2   = (const float*)d_in[13];
    const float* att2  = (const float*)d_in[14];
    // d_in[15] = bias2 : cancels inside batchnorm -> skipped
    const float* gamma2 = (const float*)d_in[16];
    const float* beta2  = (const float*)d_in[17];
    const float* Wfc   = (const float*)d_in[18];
    const float* bfc   = (const float*)d_in[19];

    const int* srcA = ei;
    const int* dstA = ei + N_EDGES;

    const size_t REG = (size_t)NPAD * FDIM * 4;
    char* p = (char*)d_ws;
    char* R0 = p;            p += REG;
    char* R1 = p;            p += REG;
    char* R2 = p;            p += REG;
    u16* WTH   = (u16*)p;              p += 512 * 256 * 2;
    u16* WTL   = (u16*)p;              p += 512 * 256 * 2;
    float* SUM = (float*)p;            p += FDIM * 4;
    float* SQ  = (float*)p;            p += FDIM * 4;
    float* SC  = (float*)p;            p += FDIM * 4;
    float* SH  = (float*)p;            p += FDIM * 4;
    int* DEG      = (int*)p;           p += (size_t)N_NODES * 4;
    int* ROWSTART = (int*)p;           p += (size_t)(N_NODES + 1) * 4;
    int* CURSOR   = (int*)p;           p += (size_t)N_NODES * 4;
    int* CSR      = (int*)p;           p += (size_t)N_EDGES * 4;
    int* BLKSUM   = (int*)p;           p += (size_t)SCAN_NBLK * 4;

    const size_t HALF = (size_t)NPAD * FDIM;  // u16 elements per half-region

    const int gat_grid = (N_NODES + 3) / 4;
    const dim3 gemm_grid_layer(NPAD / 128, 4);
    const dim3 gemm_grid_fc(NPAD / 128, 1);

    // ---------------- CSR build ----------------
    hipMemsetAsync(DEG, 0, (size_t)N_NODES * sizeof(int), stream);
    count_deg<<<2048, 256, 0, stream>>>(dstA, DEG);
    scan_phase1<<<SCAN_NBLK, SCAN_BLOCK, 0, stream>>>(DEG, BLKSUM);
    scan_phase2<<<1, 512, 0, stream>>>(BLKSUM);
    scan_phase3<<<SCAN_NBLK, SCAN_BLOCK, 0, stream>>>(DEG, BLKSUM, ROWSTART, CURSOR);
    fill_csr<<<2048, 256, 0, stream>>>(srcA, dstA, CURSOR, CSR);

    // ---------------- Layer 1 ----------------
    split_hilo<<<4096, 256, 0, stream>>>(x, N_NODES * FDIM / 4, NPAD * FDIM / 4,
                                         (u16*)R0, (u16*)R0 + HALF);
    prep_w_layer<<<512, 256, 0, stream>>>(Wl1, Wr1, WTH, WTL);
    gemm3<<<gemm_grid_layer, 256, 0, stream>>>((u16*)R0, (u16*)R0 + HALF, WTH, WTL,
                                               bl1, br1, (float*)R1, (float*)R2, 256, N_NODES);
    gat_fused<<<gat_grid, 256, 0, stream>>>((float*)R1, (float*)R2, ROWSTART, CSR, att1, (float*)R0);

    hipMemsetAsync(SUM, 0, 2 * FDIM * sizeof(float), stream);
    bn_stats<<<1024, 256, 0, stream>>>((float*)R0, SUM, SQ, N_NODES);
    bn_finalize<<<1, 256, 0, stream>>>(SUM, SQ, gamma1, beta1, SC, SH);
    bn_elu_split<<<4096, 256, 0, stream>>>((float*)R0, SC, SH, (u16*)R1, (u16*)R1 + HALF);

    // ---------------- Layer 2 ----------------
    prep_w_layer<<<512, 256, 0, stream>>>(Wl2, Wr2, WTH, WTL);
    gemm3<<<gemm_grid_layer, 256, 0, stream>>>((u16*)R1, (u16*)R1 + HALF, WTH, WTL,
                                               bl2, br2, (float*)R2, (float*)R0, 256, N_NODES);
    gat_fused<<<gat_grid, 256, 0, stream>>>((float*)R2, (float*)R0, ROWSTART, CSR, att2, (float*)R1);

    hipMemsetAsync(SUM, 0, 2 * FDIM * sizeof(float), stream);
    bn_stats<<<1024, 256, 0, stream>>>((float*)R1, SUM, SQ, N_NODES);
    bn_finalize<<<1, 256, 0, stream>>>(SUM, SQ, gamma2, beta2, SC, SH);
    bn_elu_split<<<4096, 256, 0, stream>>>((float*)R1, SC, SH, (u16*)R2, (u16*)R2 + HALF);

    // ---------------- FC + L2 normalize ----------------
    prep_w_fc<<<128, 256, 0, stream>>>(Wfc, WTH, WTL);
    gemm3<<<gemm_grid_fc, 256, 0, stream>>>((u16*)R2, (u16*)R2 + HALF, WTH, WTL,
                                            bfc, bfc, (float*)d_out, (float*)d_out, 128, N_NODES);
    l2norm<<<2048, 256, 0, stream>>>((float*)d_out, N_NODES);
}

// Round 10
// 838.263 us; speedup vs baseline: 1.1244x; 1.1244x over previous
//
#include <hip/hip_runtime.h>
#include <math.h>

#define N_NODES 100000
#define N_EDGES 800000
#define NPAD    100096   // 782 * 128
#define FDIM 256
#define HEADS 8
#define CDIM 32
#define OUTF 128

#define SCAN_BLOCK 256
#define SCAN_NBLK ((N_NODES + SCAN_BLOCK - 1) / SCAN_BLOCK)   // 391

typedef short  s16x8 __attribute__((ext_vector_type(8)));
typedef float  f32x4 __attribute__((ext_vector_type(4)));
typedef unsigned short u16;

__device__ __forceinline__ u16 f2bf(float f) {
    unsigned u = __float_as_uint(f);
    unsigned r = (u + 0x7fff + ((u >> 16) & 1)) >> 16;
    return (u16)r;
}
__device__ __forceinline__ float bf2f(u16 h) {
    return __uint_as_float(((unsigned)h) << 16);
}

__device__ __forceinline__ void gload_lds16(const void* g, void* l) {
    __builtin_amdgcn_global_load_lds((const __attribute__((address_space(1))) void*)g,
                                     (__attribute__((address_space(3))) void*)l, 16, 0, 0);
}

// ---------------- split f32 -> bf16 hi/lo (pad region zeroed) ----------------
__global__ void split_hilo(const float* __restrict__ src, int n_valid4, int n_pad4,
                           u16* __restrict__ hi, u16* __restrict__ lo) {
    int i = blockIdx.x * blockDim.x + threadIdx.x;
    int stride = gridDim.x * blockDim.x;
    for (; i < n_pad4; i += stride) {
        f32x4 v = {0.f, 0.f, 0.f, 0.f};
        if (i < n_valid4) v = ((const f32x4*)src)[i];
        u16 h[4], l[4];
#pragma unroll
        for (int j = 0; j < 4; j++) {
            float f = v[j];
            h[j] = f2bf(f);
            l[j] = f2bf(f - bf2f(h[j]));
        }
        ((ushort4*)hi)[i] = make_ushort4(h[0], h[1], h[2], h[3]);
        ((ushort4*)lo)[i] = make_ushort4(l[0], l[1], l[2], l[3]);
    }
}

// ---------------- W prep: transpose + concat + split ----------------
__global__ void prep_w_layer(const float* __restrict__ Wl, const float* __restrict__ Wr,
                             u16* __restrict__ WtH, u16* __restrict__ WtL) {
    int idx = blockIdx.x * blockDim.x + threadIdx.x;
    if (idx >= 512 * 256) return;
    int n = idx >> 8, k = idx & 255;
    float w = (n < 256) ? Wl[k * 256 + n] : Wr[k * 256 + (n - 256)];
    u16 h = f2bf(w);
    WtH[idx] = h;
    WtL[idx] = f2bf(w - bf2f(h));
}

__global__ void prep_w_fc(const float* __restrict__ Wfc,
                          u16* __restrict__ WtH, u16* __restrict__ WtL) {
    int idx = blockIdx.x * blockDim.x + threadIdx.x;
    if (idx >= 128 * 256) return;
    int n = idx >> 8, k = idx & 255;
    float w = Wfc[k * 128 + n];
    u16 h = f2bf(w);
    WtH[idx] = h;
    WtL[idx] = f2bf(w - bf2f(h));
}

// ---------------- 3-term split-precision bf16 MFMA GEMM ----------------
// BF16OUT: epilogue rounds C to bf16 (u16 arrays) -- used for the gat inputs.
template <bool BF16OUT>
__global__ __launch_bounds__(256) void gemm3(
        const u16* __restrict__ Ah, const u16* __restrict__ Al,
        const u16* __restrict__ WtH, const u16* __restrict__ WtL,
        const float* __restrict__ bias0, const float* __restrict__ bias1,
        void* __restrict__ C0v, void* __restrict__ C1v, int ldc, int M) {
    __shared__ __align__(16) u16 lA[128 * 64];
    __shared__ __align__(16) u16 lB[128 * 64];

    int tid = threadIdx.x;
    int wid = tid >> 6, lane = tid & 63;
    int wm = wid >> 1, wn = wid & 1;
    int m0 = blockIdx.x * 128, n0 = blockIdx.y * 128;
    int lr = lane & 15, lk = lane >> 4;

    f32x4 acc[4][4] = {};

#pragma unroll 1
    for (int seg = 0; seg < 3; seg++) {
        const u16* As = (seg == 1) ? Al : Ah;
        const u16* Ws = (seg == 2) ? WtL : WtH;
#pragma unroll 1
        for (int k0 = 0; k0 < 256; k0 += 64) {
#pragma unroll
            for (int i = 0; i < 4; i++) {
                int t = i * 256 + tid;
                int row = t >> 3;
                int ch = (t & 7) ^ (row & 7);
                gload_lds16(As + (size_t)(m0 + row) * 256 + k0 + ch * 8,
                            (char*)lA + i * 4096 + wid * 1024);
            }
#pragma unroll
            for (int i = 0; i < 4; i++) {
                int t = i * 256 + tid;
                int row = t >> 3;
                int ch = (t & 7) ^ (row & 7);
                gload_lds16(Ws + (size_t)(n0 + row) * 256 + k0 + ch * 8,
                            (char*)lB + i * 4096 + wid * 1024);
            }
            __syncthreads();

#pragma unroll
            for (int kk = 0; kk < 2; kk++) {
                s16x8 af[4], bf[4];
#pragma unroll
                for (int mr = 0; mr < 4; mr++) {
                    int r = wm * 64 + mr * 16 + lr;
                    int q = (kk * 4 + lk) ^ (r & 7);
                    af[mr] = *(const s16x8*)&lA[r * 64 + q * 8];
                }
#pragma unroll
                for (int nr = 0; nr < 4; nr++) {
                    int r = wn * 64 + nr * 16 + lr;
                    int q = (kk * 4 + lk) ^ (r & 7);
                    bf[nr] = *(const s16x8*)&lB[r * 64 + q * 8];
                }
#pragma unroll
                for (int mr = 0; mr < 4; mr++)
#pragma unroll
                    for (int nr = 0; nr < 4; nr++)
                        acc[mr][nr] = __builtin_amdgcn_mfma_f32_16x16x32_bf16(
                            af[mr], bf[nr], acc[mr][nr], 0, 0, 0);
            }
            __syncthreads();
        }
    }

#pragma unroll
    for (int mr = 0; mr < 4; mr++) {
#pragma unroll
        for (int nr = 0; nr < 4; nr++) {
            int col = n0 + wn * 64 + nr * 16 + lr;
            void* Cp; const float* bp; int c;
            if (col < 256) { Cp = C0v; bp = bias0; c = col; }
            else           { Cp = C1v; bp = bias1; c = col - 256; }
            float b = bp[c];
#pragma unroll
            for (int j = 0; j < 4; j++) {
                int row = m0 + wm * 64 + mr * 16 + lk * 4 + j;
                if (row < M) {
                    float v = acc[mr][nr][j] + b;
                    if constexpr (BF16OUT)
                        ((u16*)Cp)[(size_t)row * ldc + c] = f2bf(v);
                    else
                        ((float*)Cp)[(size_t)row * ldc + c] = v;
                }
            }
        }
    }
}

// ---------------- CSR build ----------------
__global__ void count_deg(const int* __restrict__ dstA, int* __restrict__ deg) {
    int i = blockIdx.x * blockDim.x + threadIdx.x;
    int stride = gridDim.x * blockDim.x;
    for (; i < N_EDGES; i += stride) atomicAdd(&deg[dstA[i]], 1);
}

__global__ void scan_phase1(const int* __restrict__ deg, int* __restrict__ blocksum) {
    __shared__ int sdata[SCAN_BLOCK];
    int i = blockIdx.x * SCAN_BLOCK + threadIdx.x;
    sdata[threadIdx.x] = (i < N_NODES) ? deg[i] : 0;
    __syncthreads();
    for (int off = SCAN_BLOCK / 2; off > 0; off >>= 1) {
        if (threadIdx.x < off) sdata[threadIdx.x] += sdata[threadIdx.x + off];
        __syncthreads();
    }
    if (threadIdx.x == 0) blocksum[blockIdx.x] = sdata[0];
}

__global__ void scan_phase2(int* __restrict__ blocksum) {
    __shared__ int part[512];
    int t = threadIdx.x;
    int v = (t < SCAN_NBLK) ? blocksum[t] : 0;
    part[t] = v;
    __syncthreads();
    for (int off = 1; off < 512; off <<= 1) {
        int u = 0;
        if (t >= off) u = part[t - off];
        __syncthreads();
        if (t >= off) part[t] += u;
        __syncthreads();
    }
    if (t < SCAN_NBLK) blocksum[t] = part[t] - v;   // exclusive
}

__global__ void scan_phase3(const int* __restrict__ deg, const int* __restrict__ blockoff,
                            int* __restrict__ rowstart, int* __restrict__ cursor) {
    __shared__ int part[SCAN_BLOCK];
    int t = threadIdx.x;
    int i = blockIdx.x * SCAN_BLOCK + t;
    int v = (i < N_NODES) ? deg[i] : 0;
    part[t] = v;
    __syncthreads();
    for (int off = 1; off < SCAN_BLOCK; off <<= 1) {
        int u = 0;
        if (t >= off) u = part[t - off];
        __syncthreads();
        if (t >= off) part[t] += u;
        __syncthreads();
    }
    if (i < N_NODES) {
        int excl = blockoff[blockIdx.x] + part[t] - v;
        rowstart[i] = excl;
        cursor[i] = excl;
        if (i == N_NODES - 1) rowstart[N_NODES] = blockoff[blockIdx.x] + part[t];
    }
}

__global__ void fill_csr(const int* __restrict__ srcA, const int* __restrict__ dstA,
                         int* __restrict__ cursor, int* __restrict__ csr_src) {
    int i = blockIdx.x * blockDim.x + threadIdx.x;
    int stride = gridDim.x * blockDim.x;
    for (; i < N_EDGES; i += stride) {
        int pos = atomicAdd(&cursor[dstA[i]], 1);
        csr_src[pos] = srcA[i];
    }
}

// ---------------- Fused GATv2 edge phase (one wave per destination) ----------------
// bf16 xl/xr tables (512 B per row): halves gather traffic; compute stays f32.
__global__ void gat_fused(const u16* __restrict__ xl, const u16* __restrict__ xr,
                          const int* __restrict__ rowstart, const int* __restrict__ csr_src,
                          const float* __restrict__ att, float* __restrict__ out) {
    int wid = (blockIdx.x * blockDim.x + threadIdx.x) >> 6;
    int lane = threadIdx.x & 63;
    if (wid >= N_NODES) return;

    ushort4 xru = *(const ushort4*)(xr + (size_t)wid * FDIM + lane * 4);
    f32x4 xrv = {bf2f(xru.x), bf2f(xru.y), bf2f(xru.z), bf2f(xru.w)};
    f32x4 attv = *(const f32x4*)(att + lane * 4);
    f32x4 acc = {0.f, 0.f, 0.f, 0.f};
    float den = 0.f;

    int jb = rowstart[wid], je = rowstart[wid + 1];
    if (jb < je) {
        int jlast = je - 1;
        // pipeline depth 3: hold rows j, j+1, j+2; load j+3
        ushort4 u0 = *(const ushort4*)(xl + (size_t)csr_src[jb] * FDIM + lane * 4);
        int j1 = (jb + 1 <= jlast) ? jb + 1 : jlast;
        ushort4 u1 = *(const ushort4*)(xl + (size_t)csr_src[j1] * FDIM + lane * 4);
        int j2 = (jb + 2 <= jlast) ? jb + 2 : jlast;
        ushort4 u2 = *(const ushort4*)(xl + (size_t)csr_src[j2] * FDIM + lane * 4);

        for (int j = jb; j < je; ++j) {
            int j3 = (j + 3 <= jlast) ? j + 3 : jlast;
            ushort4 nxt = *(const ushort4*)(xl + (size_t)csr_src[j3] * FDIM + lane * 4);

            f32x4 xv = {bf2f(u0.x), bf2f(u0.y), bf2f(u0.z), bf2f(u0.w)};
            float s = 0.f;
#pragma unroll
            for (int i = 0; i < 4; i++) {
                float v = xv[i] + xrv[i];
                v = v > 0.f ? v : 0.2f * v;
                s += v * attv[i];
            }
            // reduce over the 8-lane head group (head = lane>>3)
            s += __shfl_xor(s, 1);
            s += __shfl_xor(s, 2);
            s += __shfl_xor(s, 4);
            float e = __expf(s);
            den += e;
#pragma unroll
            for (int i = 0; i < 4; i++) acc[i] += e * xv[i];
            u0 = u1;
            u1 = u2;
            u2 = nxt;
        }
    }
    float inv = 1.f / (den + 1e-16f);
    f32x4 o;
#pragma unroll
    for (int i = 0; i < 4; i++) o[i] = acc[i] * inv;
    __builtin_nontemporal_store(o, (f32x4*)(out + (size_t)wid * FDIM + lane * 4));
}

// ---------------- BatchNorm ----------------
__global__ void bn_stats(const float* __restrict__ X, float* __restrict__ sum,
                         float* __restrict__ sumsq, int nrows) {
    int col = threadIdx.x;
    float s = 0.f, ss = 0.f;
    for (int r = blockIdx.x; r < nrows; r += gridDim.x) {
        float v = X[(size_t)r * FDIM + col];
        s += v;
        ss += v * v;
    }
    atomicAdd(&sum[col], s);
    atomicAdd(&sumsq[col], ss);
}

__global__ void bn_finalize(const float* __restrict__ sum, const float* __restrict__ sumsq,
                            const float* __restrict__ gamma, const float* __restrict__ beta,
                            float* __restrict__ scale, float* __restrict__ shift) {
    int c = threadIdx.x;
    float mean = sum[c] * (1.f / N_NODES);
    float var = sumsq[c] * (1.f / N_NODES) - mean * mean;
    float sc = gamma[c] * rsqrtf(var + 1e-5f);
    scale[c] = sc;
    shift[c] = beta[c] - mean * sc;
}

// BN + ELU fused, output split to bf16 hi/lo (pad rows zeroed)
__global__ void bn_elu_split(const float* __restrict__ X, const float* __restrict__ scale,
                             const float* __restrict__ shift,
                             u16* __restrict__ hi, u16* __restrict__ lo) {
    int i = blockIdx.x * blockDim.x + threadIdx.x;   // float4 units
    int stride = gridDim.x * blockDim.x;
    const int n_valid4 = N_NODES * FDIM / 4;
    const int n_pad4 = NPAD * FDIM / 4;
    for (; i < n_pad4; i += stride) {
        u16 h[4], l[4];
        if (i < n_valid4) {
            f32x4 v = ((const f32x4*)X)[i];
            int c0 = (i * 4) & (FDIM - 1);
#pragma unroll
            for (int j = 0; j < 4; j++) {
                float f = v[j] * scale[c0 + j] + shift[c0 + j];
                f = f > 0.f ? f : expf(f) - 1.f;
                h[j] = f2bf(f);
                l[j] = f2bf(f - bf2f(h[j]));
            }
        } else {
#pragma unroll
            for (int j = 0; j < 4; j++) { h[j] = 0; l[j] = 0; }
        }
        ((ushort4*)hi)[i] = make_ushort4(h[0], h[1], h[2], h[3]);
        ((ushort4*)lo)[i] = make_ushort4(l[0], l[1], l[2], l[3]);
    }
}

// ---------------- Row L2 normalize ----------------
__global__ void l2norm(float* __restrict__ Y, int nrows) {
    int gtid = blockIdx.x * blockDim.x + threadIdx.x;
    int wave = gtid >> 6;
    int lane = threadIdx.x & 63;
    int nwaves = (gridDim.x * blockDim.x) >> 6;
    for (int r = wave; r < nrows; r += nwaves) {
        float v0 = Y[(size_t)r * OUTF + lane];
        float v1 = Y[(size_t)r * OUTF + 64 + lane];
        float ss = v0 * v0 + v1 * v1;
        ss += __shfl_xor(ss, 32);
        ss += __shfl_xor(ss, 16);
        ss += __shfl_xor(ss, 8);
        ss += __shfl_xor(ss, 4);
        ss += __shfl_xor(ss, 2);
        ss += __shfl_xor(ss, 1);
        float inv = 1.f / fmaxf(sqrtf(ss), 1e-12f);
        Y[(size_t)r * OUTF + lane] = v0 * inv;
        Y[(size_t)r * OUTF + 64 + lane] = v1 * inv;
    }
}

extern "C" void kernel_launch(void* const* d_in, const int* in_sizes, int n_in,
                              void* d_out, int out_size, void* d_ws, size_t ws_size,
                              hipStream_t stream) {
    const float* x     = (const float*)d_in[0];
    const int*   ei    = (const int*)d_in[1];
    const float* Wl1   = (const float*)d_in[2];
    const float* bl1   = (const float*)d_in[3];
    const float* Wr1   = (const float*)d_in[4];
    const float* br1   = (const float*)d_in[5];
    const float* att1  = (const float*)d_in[6];
    // d_in[7] = bias1 : cancels exactly inside batchnorm -> skipped
    const float* gamma1 = (const float*)d_in[8];
    const float* beta1  = (const float*)d_in[9];
    const float* Wl2   = (const float*)d_in[10];
    const float* bl2   = (const float*)d_in[11];
    const float* Wr2   = (const float*)d_in[12];
    const float* br2   = (const float*)d_in[13];
    const float* att2  = (const float*)d_in[14];
    // d_in[15] = bias2 : cancels inside batchnorm -> skipped
    const float* gamma2 = (const float*)d_in[16];
    const float* beta2  = (const float*)d_in[17];
    const float* Wfc   = (const float*)d_in[18];
    const float* bfc   = (const float*)d_in[19];

    const int* srcA = ei;
    const int* dstA = ei + N_EDGES;

    const size_t REG = (size_t)NPAD * FDIM * 4;
    char* p = (char*)d_ws;
    char* R0 = p;            p += REG;
    char* R1 = p;            p += REG;
    char* R2 = p;            p += REG;
    u16* WTH   = (u16*)p;              p += 512 * 256 * 2;
    u16* WTL   = (u16*)p;              p += 512 * 256 * 2;
    float* SUM = (float*)p;            p += FDIM * 4;
    float* SQ  = (float*)p;            p += FDIM * 4;
    float* SC  = (float*)p;            p += FDIM * 4;
    float* SH  = (float*)p;            p += FDIM * 4;
    int* DEG      = (int*)p;           p += (size_t)N_NODES * 4;
    int* ROWSTART = (int*)p;           p += (size_t)(N_NODES + 1) * 4;
    int* CURSOR   = (int*)p;           p += (size_t)N_NODES * 4;
    int* CSR      = (int*)p;           p += (size_t)N_EDGES * 4;
    int* BLKSUM   = (int*)p;           p += (size_t)SCAN_NBLK * 4;

    const size_t HALF = (size_t)NPAD * FDIM;  // u16 elements per half-region

    const int gat_grid = (N_NODES + 3) / 4;
    const dim3 gemm_grid_layer(NPAD / 128, 4);
    const dim3 gemm_grid_fc(NPAD / 128, 1);

    // ---------------- CSR build ----------------
    hipMemsetAsync(DEG, 0, (size_t)N_NODES * sizeof(int), stream);
    count_deg<<<2048, 256, 0, stream>>>(dstA, DEG);
    scan_phase1<<<SCAN_NBLK, SCAN_BLOCK, 0, stream>>>(DEG, BLKSUM);
    scan_phase2<<<1, 512, 0, stream>>>(BLKSUM);
    scan_phase3<<<SCAN_NBLK, SCAN_BLOCK, 0, stream>>>(DEG, BLKSUM, ROWSTART, CURSOR);
    fill_csr<<<2048, 256, 0, stream>>>(srcA, dstA, CURSOR, CSR);

    // ---------------- Layer 1 ----------------
    // AH/AL @ R0 ; gemm -> xl(bf16) @ R1, xr(bf16) @ R2 ; gat -> O(f32) @ R0
    split_hilo<<<4096, 256, 0, stream>>>(x, N_NODES * FDIM / 4, NPAD * FDIM / 4,
                                         (u16*)R0, (u16*)R0 + HALF);
    prep_w_layer<<<512, 256, 0, stream>>>(Wl1, Wr1, WTH, WTL);
    gemm3<true><<<gemm_grid_layer, 256, 0, stream>>>((u16*)R0, (u16*)R0 + HALF, WTH, WTL,
                                                     bl1, br1, R1, R2, 256, N_NODES);
    gat_fused<<<gat_grid, 256, 0, stream>>>((u16*)R1, (u16*)R2, ROWSTART, CSR, att1, (float*)R0);

    hipMemsetAsync(SUM, 0, 2 * FDIM * sizeof(float), stream);
    bn_stats<<<1024, 256, 0, stream>>>((float*)R0, SUM, SQ, N_NODES);
    bn_finalize<<<1, 256, 0, stream>>>(SUM, SQ, gamma1, beta1, SC, SH);
    bn_elu_split<<<4096, 256, 0, stream>>>((float*)R0, SC, SH, (u16*)R1, (u16*)R1 + HALF);

    // ---------------- Layer 2 ----------------
    // AH/AL @ R1 ; gemm -> xl(bf16) @ R2, xr(bf16) @ R0 ; gat -> O(f32) @ R1
    prep_w_layer<<<512, 256, 0, stream>>>(Wl2, Wr2, WTH, WTL);
    gemm3<true><<<gemm_grid_layer, 256, 0, stream>>>((u16*)R1, (u16*)R1 + HALF, WTH, WTL,
                                                     bl2, br2, R2, R0, 256, N_NODES);
    gat_fused<<<gat_grid, 256, 0, stream>>>((u16*)R2, (u16*)R0, ROWSTART, CSR, att2, (float*)R1);

    hipMemsetAsync(SUM, 0, 2 * FDIM * sizeof(float), stream);
    bn_stats<<<1024, 256, 0, stream>>>((float*)R1, SUM, SQ, N_NODES);
    bn_finalize<<<1, 256, 0, stream>>>(SUM, SQ, gamma2, beta2, SC, SH);
    bn_elu_split<<<4096, 256, 0, stream>>>((float*)R1, SC, SH, (u16*)R2, (u16*)R2 + HALF);

    // ---------------- FC + L2 normalize ----------------
    prep_w_fc<<<128, 256, 0, stream>>>(Wfc, WTH, WTL);
    gemm3<false><<<gemm_grid_fc, 256, 0, stream>>>((u16*)R2, (u16*)R2 + HALF, WTH, WTL,
                                                   bfc, bfc, d_out, d_out, 128, N_NODES);
    l2norm<<<2048, 256, 0, stream>>>((float*)d_out, N_NODES);
}

// Round 11
// 719.616 us; speedup vs baseline: 1.3098x; 1.1649x over previous
//
#include <hip/hip_runtime.h>
#include <math.h>

#define N_NODES 100000
#define N_EDGES 800000
#define NPAD    100096   // 782 * 128
#define FDIM 256
#define HEADS 8
#define CDIM 32
#define OUTF 128

#define SCAN_BLOCK 256
#define SCAN_NBLK ((N_NODES + SCAN_BLOCK - 1) / SCAN_BLOCK)   // 391

typedef _Float16 f16x8 __attribute__((ext_vector_type(8)));
typedef float  f32x4 __attribute__((ext_vector_type(4)));
typedef unsigned short u16;

__device__ __forceinline__ u16 f2bf(float f) {
    unsigned u = __float_as_uint(f);
    unsigned r = (u + 0x7fff + ((u >> 16) & 1)) >> 16;
    return (u16)r;
}
__device__ __forceinline__ float bf2f(u16 h) {
    return __uint_as_float(((unsigned)h) << 16);
}
__device__ __forceinline__ u16 f2h(float f) {
    union { _Float16 h; u16 u; } c;
    c.h = (_Float16)f;
    return c.u;
}

__device__ __forceinline__ void gload_lds16(const void* g, void* l) {
    __builtin_amdgcn_global_load_lds((const __attribute__((address_space(1))) void*)g,
                                     (__attribute__((address_space(3))) void*)l, 16, 0, 0);
}

// ---------------- cast f32 -> fp16 (pad region zeroed) ----------------
__global__ void cast_half(const float* __restrict__ src, int n_valid4, int n_pad4,
                          u16* __restrict__ dst) {
    int i = blockIdx.x * blockDim.x + threadIdx.x;
    int stride = gridDim.x * blockDim.x;
    for (; i < n_pad4; i += stride) {
        f32x4 v = {0.f, 0.f, 0.f, 0.f};
        if (i < n_valid4) v = ((const f32x4*)src)[i];
        ((ushort4*)dst)[i] = make_ushort4(f2h(v[0]), f2h(v[1]), f2h(v[2]), f2h(v[3]));
    }
}

// ---------------- W prep: transpose + concat, fp16 ----------------
__global__ void prep_w_layer(const float* __restrict__ Wl, const float* __restrict__ Wr,
                             u16* __restrict__ Wt) {
    int idx = blockIdx.x * blockDim.x + threadIdx.x;
    if (idx >= 512 * 256) return;
    int n = idx >> 8, k = idx & 255;
    float w = (n < 256) ? Wl[k * 256 + n] : Wr[k * 256 + (n - 256)];
    Wt[idx] = f2h(w);
}

__global__ void prep_w_fc(const float* __restrict__ Wfc, u16* __restrict__ Wt) {
    int idx = blockIdx.x * blockDim.x + threadIdx.x;
    if (idx >= 128 * 256) return;
    int n = idx >> 8, k = idx & 255;
    Wt[idx] = f2h(Wfc[k * 128 + n]);
}

// ---------------- single-pass fp16 MFMA GEMM ----------------
// C = A@W + bias. BF16OUT: epilogue rounds C to bf16 (gat inputs); else f32.
// A: fp16 [NPAD][256]. Wt: fp16 [NB][256] (W transposed). 128x128 tile, BK=64.
template <bool BF16OUT>
__global__ __launch_bounds__(256) void gemm_h(
        const u16* __restrict__ A, const u16* __restrict__ Wt,
        const float* __restrict__ bias0, const float* __restrict__ bias1,
        void* __restrict__ C0v, void* __restrict__ C1v, int ldc, int M) {
    __shared__ __align__(16) u16 lA[128 * 64];
    __shared__ __align__(16) u16 lB[128 * 64];

    int tid = threadIdx.x;
    int wid = tid >> 6, lane = tid & 63;
    int wm = wid >> 1, wn = wid & 1;
    int m0 = blockIdx.x * 128, n0 = blockIdx.y * 128;
    int lr = lane & 15, lk = lane >> 4;

    f32x4 acc[4][4] = {};

#pragma unroll 1
    for (int k0 = 0; k0 < 256; k0 += 64) {
#pragma unroll
        for (int i = 0; i < 4; i++) {
            int t = i * 256 + tid;
            int row = t >> 3;
            int ch = (t & 7) ^ (row & 7);
            gload_lds16(A + (size_t)(m0 + row) * 256 + k0 + ch * 8,
                        (char*)lA + i * 4096 + wid * 1024);
        }
#pragma unroll
        for (int i = 0; i < 4; i++) {
            int t = i * 256 + tid;
            int row = t >> 3;
            int ch = (t & 7) ^ (row & 7);
            gload_lds16(Wt + (size_t)(n0 + row) * 256 + k0 + ch * 8,
                        (char*)lB + i * 4096 + wid * 1024);
        }
        __syncthreads();

#pragma unroll
        for (int kk = 0; kk < 2; kk++) {
            f16x8 af[4], bf[4];
#pragma unroll
            for (int mr = 0; mr < 4; mr++) {
                int r = wm * 64 + mr * 16 + lr;
                int q = (kk * 4 + lk) ^ (r & 7);
                af[mr] = *(const f16x8*)&lA[r * 64 + q * 8];
            }
#pragma unroll
            for (int nr = 0; nr < 4; nr++) {
                int r = wn * 64 + nr * 16 + lr;
                int q = (kk * 4 + lk) ^ (r & 7);
                bf[nr] = *(const f16x8*)&lB[r * 64 + q * 8];
            }
#pragma unroll
            for (int mr = 0; mr < 4; mr++)
#pragma unroll
                for (int nr = 0; nr < 4; nr++)
                    acc[mr][nr] = __builtin_amdgcn_mfma_f32_16x16x32_f16(
                        af[mr], bf[nr], acc[mr][nr], 0, 0, 0);
        }
        __syncthreads();
    }

    // epilogue: C row = (lane>>4)*4 + j, col = lane&15 (m89-verified layout)
#pragma unroll
    for (int mr = 0; mr < 4; mr++) {
#pragma unroll
        for (int nr = 0; nr < 4; nr++) {
            int col = n0 + wn * 64 + nr * 16 + lr;
            void* Cp; const float* bp; int c;
            if (col < 256) { Cp = C0v; bp = bias0; c = col; }
            else           { Cp = C1v; bp = bias1; c = col - 256; }
            float b = bp[c];
#pragma unroll
            for (int j = 0; j < 4; j++) {
                int row = m0 + wm * 64 + mr * 16 + lk * 4 + j;
                if (row < M) {
                    float v = acc[mr][nr][j] + b;
                    if constexpr (BF16OUT)
                        ((u16*)Cp)[(size_t)row * ldc + c] = f2bf(v);
                    else
                        ((float*)Cp)[(size_t)row * ldc + c] = v;
                }
            }
        }
    }
}

// ---------------- CSR build ----------------
__global__ void count_deg(const int* __restrict__ dstA, int* __restrict__ deg) {
    int i = blockIdx.x * blockDim.x + threadIdx.x;
    int stride = gridDim.x * blockDim.x;
    for (; i < N_EDGES; i += stride) atomicAdd(&deg[dstA[i]], 1);
}

__global__ void scan_phase1(const int* __restrict__ deg, int* __restrict__ blocksum) {
    __shared__ int sdata[SCAN_BLOCK];
    int i = blockIdx.x * SCAN_BLOCK + threadIdx.x;
    sdata[threadIdx.x] = (i < N_NODES) ? deg[i] : 0;
    __syncthreads();
    for (int off = SCAN_BLOCK / 2; off > 0; off >>= 1) {
        if (threadIdx.x < off) sdata[threadIdx.x] += sdata[threadIdx.x + off];
        __syncthreads();
    }
    if (threadIdx.x == 0) blocksum[blockIdx.x] = sdata[0];
}

__global__ void scan_phase2(int* __restrict__ blocksum) {
    __shared__ int part[512];
    int t = threadIdx.x;
    int v = (t < SCAN_NBLK) ? blocksum[t] : 0;
    part[t] = v;
    __syncthreads();
    for (int off = 1; off < 512; off <<= 1) {
        int u = 0;
        if (t >= off) u = part[t - off];
        __syncthreads();
        if (t >= off) part[t] += u;
        __syncthreads();
    }
    if (t < SCAN_NBLK) blocksum[t] = part[t] - v;   // exclusive
}

__global__ void scan_phase3(const int* __restrict__ deg, const int* __restrict__ blockoff,
                            int* __restrict__ rowstart, int* __restrict__ cursor) {
    __shared__ int part[SCAN_BLOCK];
    int t = threadIdx.x;
    int i = blockIdx.x * SCAN_BLOCK + t;
    int v = (i < N_NODES) ? deg[i] : 0;
    part[t] = v;
    __syncthreads();
    for (int off = 1; off < SCAN_BLOCK; off <<= 1) {
        int u = 0;
        if (t >= off) u = part[t - off];
        __syncthreads();
        if (t >= off) part[t] += u;
        __syncthreads();
    }
    if (i < N_NODES) {
        int excl = blockoff[blockIdx.x] + part[t] - v;
        rowstart[i] = excl;
        cursor[i] = excl;
        if (i == N_NODES - 1) rowstart[N_NODES] = blockoff[blockIdx.x] + part[t];
    }
}

__global__ void fill_csr(const int* __restrict__ srcA, const int* __restrict__ dstA,
                         int* __restrict__ cursor, int* __restrict__ csr_src) {
    int i = blockIdx.x * blockDim.x + threadIdx.x;
    int stride = gridDim.x * blockDim.x;
    for (; i < N_EDGES; i += stride) {
        int pos = atomicAdd(&cursor[dstA[i]], 1);
        csr_src[pos] = srcA[i];
    }
}

// ---------------- Fused GATv2 edge phase (one wave per destination) ----------------
// bf16 xl/xr tables (512 B per row); depth-3 pipeline; compute f32.
__global__ void gat_fused(const u16* __restrict__ xl, const u16* __restrict__ xr,
                          const int* __restrict__ rowstart, const int* __restrict__ csr_src,
                          const float* __restrict__ att, float* __restrict__ out) {
    int wid = (blockIdx.x * blockDim.x + threadIdx.x) >> 6;
    int lane = threadIdx.x & 63;
    if (wid >= N_NODES) return;

    ushort4 xru = *(const ushort4*)(xr + (size_t)wid * FDIM + lane * 4);
    f32x4 xrv = {bf2f(xru.x), bf2f(xru.y), bf2f(xru.z), bf2f(xru.w)};
    f32x4 attv = *(const f32x4*)(att + lane * 4);
    f32x4 acc = {0.f, 0.f, 0.f, 0.f};
    float den = 0.f;

    int jb = rowstart[wid], je = rowstart[wid + 1];
    if (jb < je) {
        int jlast = je - 1;
        ushort4 u0 = *(const ushort4*)(xl + (size_t)csr_src[jb] * FDIM + lane * 4);
        int j1 = (jb + 1 <= jlast) ? jb + 1 : jlast;
        ushort4 u1 = *(const ushort4*)(xl + (size_t)csr_src[j1] * FDIM + lane * 4);
        int j2 = (jb + 2 <= jlast) ? jb + 2 : jlast;
        ushort4 u2 = *(const ushort4*)(xl + (size_t)csr_src[j2] * FDIM + lane * 4);

        for (int j = jb; j < je; ++j) {
            int j3 = (j + 3 <= jlast) ? j + 3 : jlast;
            ushort4 nxt = *(const ushort4*)(xl + (size_t)csr_src[j3] * FDIM + lane * 4);

            f32x4 xv = {bf2f(u0.x), bf2f(u0.y), bf2f(u0.z), bf2f(u0.w)};
            float s = 0.f;
#pragma unroll
            for (int i = 0; i < 4; i++) {
                float v = xv[i] + xrv[i];
                v = v > 0.f ? v : 0.2f * v;
                s += v * attv[i];
            }
            s += __shfl_xor(s, 1);
            s += __shfl_xor(s, 2);
            s += __shfl_xor(s, 4);
            float e = __expf(s);
            den += e;
#pragma unroll
            for (int i = 0; i < 4; i++) acc[i] += e * xv[i];
            u0 = u1;
            u1 = u2;
            u2 = nxt;
        }
    }
    float inv = 1.f / (den + 1e-16f);
    f32x4 o;
#pragma unroll
    for (int i = 0; i < 4; i++) o[i] = acc[i] * inv;
    __builtin_nontemporal_store(o, (f32x4*)(out + (size_t)wid * FDIM + lane * 4));
}

// ---------------- BatchNorm ----------------
__global__ void bn_stats(const float* __restrict__ X, float* __restrict__ sum,
                         float* __restrict__ sumsq, int nrows) {
    int col = threadIdx.x;
    float s = 0.f, ss = 0.f;
    for (int r = blockIdx.x; r < nrows; r += gridDim.x) {
        float v = X[(size_t)r * FDIM + col];
        s += v;
        ss += v * v;
    }
    atomicAdd(&sum[col], s);
    atomicAdd(&sumsq[col], ss);
}

__global__ void bn_finalize(const float* __restrict__ sum, const float* __restrict__ sumsq,
                            const float* __restrict__ gamma, const float* __restrict__ beta,
                            float* __restrict__ scale, float* __restrict__ shift) {
    int c = threadIdx.x;
    float mean = sum[c] * (1.f / N_NODES);
    float var = sumsq[c] * (1.f / N_NODES) - mean * mean;
    float sc = gamma[c] * rsqrtf(var + 1e-5f);
    scale[c] = sc;
    shift[c] = beta[c] - mean * sc;
}

// BN + ELU fused, output fp16 (pad rows zeroed)
__global__ void bn_elu_half(const float* __restrict__ X, const float* __restrict__ scale,
                            const float* __restrict__ shift, u16* __restrict__ dst) {
    int i = blockIdx.x * blockDim.x + threadIdx.x;   // float4 units
    int stride = gridDim.x * blockDim.x;
    const int n_valid4 = N_NODES * FDIM / 4;
    const int n_pad4 = NPAD * FDIM / 4;
    for (; i < n_pad4; i += stride) {
        u16 h[4] = {0, 0, 0, 0};
        if (i < n_valid4) {
            f32x4 v = ((const f32x4*)X)[i];
            int c0 = (i * 4) & (FDIM - 1);
#pragma unroll
            for (int j = 0; j < 4; j++) {
                float f = v[j] * scale[c0 + j] + shift[c0 + j];
                f = f > 0.f ? f : expf(f) - 1.f;
                h[j] = f2h(f);
            }
        }
        ((ushort4*)dst)[i] = make_ushort4(h[0], h[1], h[2], h[3]);
    }
}

// ---------------- Row L2 normalize ----------------
__global__ void l2norm(float* __restrict__ Y, int nrows) {
    int gtid = blockIdx.x * blockDim.x + threadIdx.x;
    int wave = gtid >> 6;
    int lane = threadIdx.x & 63;
    int nwaves = (gridDim.x * blockDim.x) >> 6;
    for (int r = wave; r < nrows; r += nwaves) {
        float v0 = Y[(size_t)r * OUTF + lane];
        float v1 = Y[(size_t)r * OUTF + 64 + lane];
        float ss = v0 * v0 + v1 * v1;
        ss += __shfl_xor(ss, 32);
        ss += __shfl_xor(ss, 16);
        ss += __shfl_xor(ss, 8);
        ss += __shfl_xor(ss, 4);
        ss += __shfl_xor(ss, 2);
        ss += __shfl_xor(ss, 1);
        float inv = 1.f / fmaxf(sqrtf(ss), 1e-12f);
        Y[(size_t)r * OUTF + lane] = v0 * inv;
        Y[(size_t)r * OUTF + 64 + lane] = v1 * inv;
    }
}

extern "C" void kernel_launch(void* const* d_in, const int* in_sizes, int n_in,
                              void* d_out, int out_size, void* d_ws, size_t ws_size,
                              hipStream_t stream) {
    const float* x     = (const float*)d_in[0];
    const int*   ei    = (const int*)d_in[1];
    const float* Wl1   = (const float*)d_in[2];
    const float* bl1   = (const float*)d_in[3];
    const float* Wr1   = (const float*)d_in[4];
    const float* br1   = (const float*)d_in[5];
    const float* att1  = (const float*)d_in[6];
    // d_in[7] = bias1 : cancels exactly inside batchnorm -> skipped
    const float* gamma1 = (const float*)d_in[8];
    const float* beta1  = (const float*)d_in[9];
    const float* Wl2   = (const float*)d_in[10];
    const float* bl2   = (const float*)d_in[11];
    const float* Wr2   = (const float*)d_in[12];
    const float* br2   = (const float*)d_in[13];
    const float* att2  = (const float*)d_in[14];
    // d_in[15] = bias2 : cancels inside batchnorm -> skipped
    const float* gamma2 = (const float*)d_in[16];
    const float* beta2  = (const float*)d_in[17];
    const float* Wfc   = (const float*)d_in[18];
    const float* bfc   = (const float*)d_in[19];

    const int* srcA = ei;
    const int* dstA = ei + N_EDGES;

    const size_t REG = (size_t)NPAD * FDIM * 4;
    char* p = (char*)d_ws;
    char* R0 = p;            p += REG;
    char* R1 = p;            p += REG;
    char* R2 = p;            p += REG;
    u16* WTH   = (u16*)p;              p += 512 * 256 * 2;
    float* SUM = (float*)p;            p += FDIM * 4;
    float* SQ  = (float*)p;            p += FDIM * 4;
    float* SC  = (float*)p;            p += FDIM * 4;
    float* SH  = (float*)p;            p += FDIM * 4;
    int* DEG      = (int*)p;           p += (size_t)N_NODES * 4;
    int* ROWSTART = (int*)p;           p += (size_t)(N_NODES + 1) * 4;
    int* CURSOR   = (int*)p;           p += (size_t)N_NODES * 4;
    int* CSR      = (int*)p;           p += (size_t)N_EDGES * 4;
    int* BLKSUM   = (int*)p;           p += (size_t)SCAN_NBLK * 4;

    const int gat_grid = (N_NODES + 3) / 4;
    const dim3 gemm_grid_layer(NPAD / 128, 4);
    const dim3 gemm_grid_fc(NPAD / 128, 1);

    // ---------------- CSR build ----------------
    hipMemsetAsync(DEG, 0, (size_t)N_NODES * sizeof(int), stream);
    count_deg<<<2048, 256, 0, stream>>>(dstA, DEG);
    scan_phase1<<<SCAN_NBLK, SCAN_BLOCK, 0, stream>>>(DEG, BLKSUM);
    scan_phase2<<<1, 512, 0, stream>>>(BLKSUM);
    scan_phase3<<<SCAN_NBLK, SCAN_BLOCK, 0, stream>>>(DEG, BLKSUM, ROWSTART, CURSOR);
    fill_csr<<<2048, 256, 0, stream>>>(srcA, dstA, CURSOR, CSR);

    // ---------------- Layer 1 ----------------
    // A(fp16) @ R0 ; gemm -> xl(bf16) @ R1, xr(bf16) @ R2 ; gat -> O(f32) @ R0
    cast_half<<<4096, 256, 0, stream>>>(x, N_NODES * FDIM / 4, NPAD * FDIM / 4, (u16*)R0);
    prep_w_layer<<<512, 256, 0, stream>>>(Wl1, Wr1, WTH);
    gemm_h<true><<<gemm_grid_layer, 256, 0, stream>>>((u16*)R0, WTH, bl1, br1, R1, R2, 256, N_NODES);
    gat_fused<<<gat_grid, 256, 0, stream>>>((u16*)R1, (u16*)R2, ROWSTART, CSR, att1, (float*)R0);

    hipMemsetAsync(SUM, 0, 2 * FDIM * sizeof(float), stream);
    bn_stats<<<1024, 256, 0, stream>>>((float*)R0, SUM, SQ, N_NODES);
    bn_finalize<<<1, 256, 0, stream>>>(SUM, SQ, gamma1, beta1, SC, SH);
    bn_elu_half<<<4096, 256, 0, stream>>>((float*)R0, SC, SH, (u16*)R1);

    // ---------------- Layer 2 ----------------
    // A(fp16) @ R1 ; gemm -> xl(bf16) @ R2, xr(bf16) @ R0 ; gat -> O(f32) @ R1
    prep_w_layer<<<512, 256, 0, stream>>>(Wl2, Wr2, WTH);
    gemm_h<true><<<gemm_grid_layer, 256, 0, stream>>>((u16*)R1, WTH, bl2, br2, R2, R0, 256, N_NODES);
    gat_fused<<<gat_grid, 256, 0, stream>>>((u16*)R2, (u16*)R0, ROWSTART, CSR, att2, (float*)R1);

    hipMemsetAsync(SUM, 0, 2 * FDIM * sizeof(float), stream);
    bn_stats<<<1024, 256, 0, stream>>>((float*)R1, SUM, SQ, N_NODES);
    bn_finalize<<<1, 256, 0, stream>>>(SUM, SQ, gamma2, beta2, SC, SH);
    bn_elu_half<<<4096, 256, 0, stream>>>((float*)R1, SC, SH, (u16*)R2);

    // ---------------- FC + L2 normalize ----------------
    prep_w_fc<<<128, 256, 0, stream>>>(Wfc, WTH);
    gemm_h<false><<<gemm_grid_fc, 256, 0, stream>>>((u16*)R2, WTH, bfc, bfc, d_out, d_out, 128, N_NODES);
    l2norm<<<2048, 256, 0, stream>>>((float*)d_out, N_NODES);
}